// Round 1
// baseline (33479.929 us; speedup 1.0000x reference)
//
#include <hip/hip_runtime.h>
#include <math.h>

#define BB 128
#define TT 512
#define FF 128
#define HH 512
#define NG 2048

__global__ __launch_bounds__(256) void k_zero(float* __restrict__ p, int n) {
  int i = blockIdx.x * 256 + threadIdx.x;
  if (i < n) p[i] = 0.f;
}

// xT[(t*FF+f)*BB + b] = x[b][t][f]
__global__ __launch_bounds__(256) void k_transpose_x(const float* __restrict__ x,
                                                     float* __restrict__ xT) {
  int e = blockIdx.x * 256 + threadIdx.x;
  int b = e & (BB - 1);
  int f = (e >> 7) & (FF - 1);
  int t = e >> 14;
  xT[e] = x[(size_t)b * (TT * FF) + t * FF + f];
}

// dst[(j*K + k)*4 + g] = src[k*NG + g*HH + j]   (gate-interleaved, column-major by j)
__global__ __launch_bounds__(256) void k_rearrange(const float* __restrict__ src,
                                                   float* __restrict__ dst,
                                                   int kmask, int kshift) {
  int e = blockIdx.x * 256 + threadIdx.x;
  int g = e & 3;
  int k = (e >> 2) & kmask;
  int j = e >> (2 + kshift);
  dst[e] = src[k * NG + g * HH + j];
}

// One timestep: z = h_in @ U + x_t @ W + b; gates; update c; write h_out.
// Layouts: h_in/h_out/cT/xt are [K][B] column-major. Uc/Wc are [j][k][4].
// Grid 256 blocks x 256 threads: thread = (b = tid&127, jl = tid>>7), j = bx*2+jl.
// jl is wave-uniform -> U/W loads become scalar s_load_dwordx4; only per-lane
// VMEM is the coalesced h/x read (lanes = consecutive b).
__global__ __launch_bounds__(256) void k_step(
    const float* __restrict__ Uc, const float* __restrict__ Wc,
    const float* __restrict__ bias, const float* __restrict__ xt,
    const float* __restrict__ h_in, float* __restrict__ h_out,
    float* __restrict__ cT, int KX)
{
  int tid = threadIdx.x;
  int b = tid & (BB - 1);
  int jl = tid >> 7;
  int j = __builtin_amdgcn_readfirstlane((int)(blockIdx.x * 2 + jl));
  const float* __restrict__ up = Uc + (size_t)j * HH * 4;
  const float* __restrict__ wp = Wc + (size_t)j * KX * 4;
  float a0 = bias[j];
  float a1 = bias[HH + j];
  float a2 = bias[2 * HH + j];
  float a3 = bias[3 * HH + j];
#pragma unroll 8
  for (int k = 0; k < HH; ++k) {
    float hv = h_in[k * BB + b];
    a0 = fmaf(hv, up[k * 4 + 0], a0);
    a1 = fmaf(hv, up[k * 4 + 1], a1);
    a2 = fmaf(hv, up[k * 4 + 2], a2);
    a3 = fmaf(hv, up[k * 4 + 3], a3);
  }
#pragma unroll 8
  for (int k = 0; k < KX; ++k) {
    float xv = xt[k * BB + b];
    a0 = fmaf(xv, wp[k * 4 + 0], a0);
    a1 = fmaf(xv, wp[k * 4 + 1], a1);
    a2 = fmaf(xv, wp[k * 4 + 2], a2);
    a3 = fmaf(xv, wp[k * 4 + 3], a3);
  }
  float ig = 1.f / (1.f + __expf(-a0));
  float fg = 1.f / (1.f + __expf(-a1));
  float gg = tanhf(a2);
  float og = 1.f / (1.f + __expf(-a3));
  int idx = j * BB + b;
  float cv = fg * cT[idx] + ig * gg;
  float hn = og * tanhf(cv);
  cT[idx] = cv;
  h_out[idx] = hn;
}

// logits = h2 @ Wd + bd; softmax.  h2 is [H][B] column-major.
__global__ __launch_bounds__(64) void k_dense(const float* __restrict__ h2,
                                              const float* __restrict__ Wd,
                                              const float* __restrict__ bd,
                                              float* __restrict__ out) {
  int b = blockIdx.x * 64 + threadIdx.x;
  float acc[10];
#pragma unroll
  for (int c = 0; c < 10; ++c) acc[c] = bd[c];
  for (int k = 0; k < HH; ++k) {
    float hv = h2[k * BB + b];
#pragma unroll
    for (int c = 0; c < 10; ++c) acc[c] = fmaf(hv, Wd[k * 10 + c], acc[c]);
  }
  float m = acc[0];
#pragma unroll
  for (int c = 1; c < 10; ++c) m = fmaxf(m, acc[c]);
  float s = 0.f;
#pragma unroll
  for (int c = 0; c < 10; ++c) { acc[c] = __expf(acc[c] - m); s += acc[c]; }
  float inv = 1.f / s;
#pragma unroll
  for (int c = 0; c < 10; ++c) out[b * 10 + c] = acc[c] * inv;
}

extern "C" void kernel_launch(void* const* d_in, const int* in_sizes, int n_in,
                              void* d_out, int out_size, void* d_ws, size_t ws_size,
                              hipStream_t stream) {
  const float* x  = (const float*)d_in[0];
  const float* W1 = (const float*)d_in[1];
  const float* U1 = (const float*)d_in[2];
  const float* b1 = (const float*)d_in[3];
  const float* W2 = (const float*)d_in[4];
  const float* U2 = (const float*)d_in[5];
  const float* b2 = (const float*)d_in[6];
  const float* Wd = (const float*)d_in[7];
  const float* bd = (const float*)d_in[8];
  float* out = (float*)d_out;

  float* ws    = (float*)d_ws;
  float* xT    = ws;                        // [T][F][B]   8,388,608
  float* seqT  = xT + (size_t)TT*FF*BB;     // [T][H][B]  33,554,432
  float* hzero = seqT + (size_t)TT*HH*BB;   // [H][B]     65,536 (zeroed)
  float* cT    = hzero + HH*BB;             // [H][B]     65,536 (zeroed)
  float* hA    = cT + HH*BB;                // [H][B]
  float* hB    = hA + HH*BB;                // [H][B]
  float* Uc1   = hB + HH*BB;                // [512][512][4]
  float* Wc1   = Uc1 + (size_t)HH*NG;       // [512][128][4]
  float* Uc2   = Wc1 + (size_t)FF*NG;       // [512][512][4]
  float* Wc2   = Uc2 + (size_t)HH*NG;       // [512][512][4]
  // total ws: ~181 MB fp32

  // prep (re-done every call; ws/out are re-poisoned by the harness)
  k_zero<<<(2*HH*BB)/256, 256, 0, stream>>>(hzero, 2*HH*BB);   // hzero + cT adjacent
  k_transpose_x<<<(TT*FF*BB)/256, 256, 0, stream>>>(x, xT);
  k_rearrange<<<(HH*NG)/256, 256, 0, stream>>>(U1, Uc1, HH-1, 9);
  k_rearrange<<<(FF*NG)/256, 256, 0, stream>>>(W1, Wc1, FF-1, 7);
  k_rearrange<<<(HH*NG)/256, 256, 0, stream>>>(U2, Uc2, HH-1, 9);
  k_rearrange<<<(HH*NG)/256, 256, 0, stream>>>(W2, Wc2, HH-1, 9);

  // layer 1: h outputs written straight into seqT[t] (doubles as double-buffer)
  for (int t = 0; t < TT; ++t) {
    const float* h_in = (t == 0) ? hzero : (seqT + (size_t)(t-1)*HH*BB);
    float* h_out = seqT + (size_t)t*HH*BB;
    k_step<<<256, 256, 0, stream>>>(Uc1, Wc1, b1, xT + (size_t)t*FF*BB,
                                    h_in, h_out, cT, FF);
  }
  // layer 2: initial (h,c) = layer-1 final state (seqT[T-1], cT left in place)
  for (int t = 0; t < TT; ++t) {
    const float* h_in = (t == 0) ? (seqT + (size_t)(TT-1)*HH*BB)
                                 : ((t & 1) ? hA : hB);
    float* h_out = (t & 1) ? hB : hA;   // t=511 -> hB
    k_step<<<256, 256, 0, stream>>>(Uc2, Wc2, b2, seqT + (size_t)t*HH*BB,
                                    h_in, h_out, cT, HH);
  }
  k_dense<<<BB/64, 64, 0, stream>>>(hB, Wd, bd, out);
}